// Round 1
// baseline (299.598 us; speedup 1.0000x reference)
//
#include <hip/hip_runtime.h>
#include <math.h>

#define BATCH 64
#define IMH 512
#define IMW 512
#define UNITS 256

// workspace layout (float offsets); ws is ~768 MiB, we use 192 KB
#define WS_XT   0        // xT[256][64]  : x   transposed, xT[k][b]
#define WS_H0T  16384    // h0T[256][64] : h0  transposed
#define WS_C0T  32768    // c0T[256][64] : c0  transposed

__device__ __forceinline__ float sigmoidf_(float x) {
    return 1.0f / (1.0f + __expf(-x));
}
__device__ __forceinline__ float tanhf_(float x) {
    float e = __expf(2.0f * x);
    return 1.0f - 2.0f / (e + 1.0f);
}

// ---------------------------------------------------------------------------
// K1: interp + conv1 + conv2 + dense quarter. 256 blocks = 64 batches x 4
// column-quarters. conv/interp redundantly recomputed per quarter (trivial);
// dense weight traffic per block drops 442KB -> 110KB.
// ---------------------------------------------------------------------------
__global__ __launch_bounds__(256) void prep_kernel(
    const float* __restrict__ image,    // (64,512,512,3)
    const float* __restrict__ section,  // (64,3)
    const float* __restrict__ h0,       // (64,256)
    const float* __restrict__ c0,       // (64,256)
    const float* __restrict__ k1,       // (3,3,3,3)
    const float* __restrict__ b1,
    const float* __restrict__ k2,
    const float* __restrict__ b2,
    const float* __restrict__ dw,       // (432,256)
    const float* __restrict__ db,       // (256,)
    float* __restrict__ ws)
{
    const int b   = blockIdx.x >> 2;
    const int q   = blockIdx.x & 3;
    const int tid = threadIdx.x;

    __shared__ float s_sec[16][16][3];
    __shared__ float s_c1[14][14][3];
    __shared__ float s_flat[432];
    __shared__ float s_part[4][64];
    __shared__ float s_k1[84];
    __shared__ float s_k2[84];

    if (tid < 81)       s_k1[tid]      = k1[tid];
    else if (tid < 84)  s_k1[tid]      = b1[tid - 81];
    else if (tid < 165) s_k2[tid - 84] = k2[tid - 84];
    else if (tid < 168) s_k2[tid - 84] = b2[tid - 165];

    // ---- bilinear interpolation: 16x16 grid, one thread per grid point ----
    {
        const float s0 = section[b * 3 + 0];
        const float s1 = section[b * 3 + 1];
        const float s2 = section[b * 3 + 2];
        const int i = tid >> 4, j = tid & 15;
        float p0 = s0 + (float)i * (1.0f / 15.0f) * s2;
        float p1 = s1 + (float)j * (1.0f / 15.0f) * s2;
        float fy = fminf(fmaxf(p0 * 511.0f, 0.0f), 511.0f);
        float fx = fminf(fmaxf(p1 * 511.0f, 0.0f), 511.0f);
        int y0 = (int)floorf(fy);
        int x0 = (int)floorf(fx);
        int y1 = min(y0 + 1, 511);
        int x1 = min(x0 + 1, 511);
        float wy = fy - (float)y0;
        float wx = fx - (float)x0;
        const float* base = image + (size_t)b * IMH * IMW * 3;
        const float* p00 = base + (y0 * IMW + x0) * 3;
        const float* p01 = base + (y0 * IMW + x1) * 3;
        const float* p10 = base + (y1 * IMW + x0) * 3;
        const float* p11 = base + (y1 * IMW + x1) * 3;
        #pragma unroll
        for (int c = 0; c < 3; ++c) {
            float top = p00[c] * (1.0f - wx) + p01[c] * wx;
            float bot = p10[c] * (1.0f - wx) + p11[c] * wx;
            s_sec[i][j][c] = top * (1.0f - wy) + bot * wy;
        }
    }
    __syncthreads();

    // ---- conv1 (3x3 VALID, 3->3) + relu : 16x16 -> 14x14 ----
    if (tid < 196) {
        const int i = tid / 14, j = tid % 14;
        float a0 = s_k1[81], a1 = s_k1[82], a2 = s_k1[83];
        #pragma unroll
        for (int di = 0; di < 3; ++di)
            #pragma unroll
            for (int dj = 0; dj < 3; ++dj)
                #pragma unroll
                for (int ci = 0; ci < 3; ++ci) {
                    float v = s_sec[i + di][j + dj][ci];
                    const int kb = ((di * 3 + dj) * 3 + ci) * 3;
                    a0 += v * s_k1[kb + 0];
                    a1 += v * s_k1[kb + 1];
                    a2 += v * s_k1[kb + 2];
                }
        s_c1[i][j][0] = fmaxf(a0, 0.0f);
        s_c1[i][j][1] = fmaxf(a1, 0.0f);
        s_c1[i][j][2] = fmaxf(a2, 0.0f);
    }
    __syncthreads();

    // ---- conv2 (3x3 VALID, 3->3) + relu : 14x14 -> 12x12, flatten ----
    if (tid < 144) {
        const int i = tid / 12, j = tid % 12;
        float a0 = s_k2[81], a1 = s_k2[82], a2 = s_k2[83];
        #pragma unroll
        for (int di = 0; di < 3; ++di)
            #pragma unroll
            for (int dj = 0; dj < 3; ++dj)
                #pragma unroll
                for (int ci = 0; ci < 3; ++ci) {
                    float v = s_c1[i + di][j + dj][ci];
                    const int kb = ((di * 3 + dj) * 3 + ci) * 3;
                    a0 += v * s_k2[kb + 0];
                    a1 += v * s_k2[kb + 1];
                    a2 += v * s_k2[kb + 2];
                }
        const int fb = tid * 3;
        s_flat[fb + 0] = fmaxf(a0, 0.0f);
        s_flat[fb + 1] = fmaxf(a1, 0.0f);
        s_flat[fb + 2] = fmaxf(a2, 0.0f);
    }
    __syncthreads();

    // ---- dense quarter: 64 cols, 4-way K split (432 = 4*108) ----
    {
        const int l = tid & 63, kg = tid >> 6;
        const int col = q * 64 + l;
        const float* wp = dw + (kg * 108) * 256 + col;
        const float* fp = s_flat + kg * 108;
        float acc = 0.0f;
        #pragma unroll 6
        for (int k = 0; k < 108; ++k)
            acc += fp[k] * wp[k * 256];
        s_part[kg][l] = acc;
    }
    __syncthreads();
    if (tid < 64) {
        const int col = q * 64 + tid;
        float x = fmaxf(s_part[0][tid] + s_part[1][tid] + s_part[2][tid] +
                        s_part[3][tid] + db[col], 0.0f);
        ws[WS_XT + col * 64 + b] = x;               // xT[col][b]
    }
    if (q == 0) {
        // transpose h0, c0 into ws so K2 can stage them conflict-free
        ws[WS_H0T + tid * 64 + b] = h0[b * 256 + tid];
        ws[WS_C0T + tid * 64 + b] = c0[b * 256 + tid];
    }
}

// ---------------------------------------------------------------------------
// K2: LSTM, column-parallel. 128 blocks; block j owns columns {2j, 2j+1} of
// EACH of the 4 gates, for all 64 batches. Every weight byte of lk/lrk is
// read by exactly ONE block (total 2 MB, was 128 MB). x/h0 staged in LDS as
// [k][b] so the 64 lanes (over b) read consecutive floats -> conflict-free.
// ---------------------------------------------------------------------------
__global__ __launch_bounds__(512) void lstm_kernel(
    const float* __restrict__ lk,       // (256,1024)
    const float* __restrict__ lrk,      // (256,1024)
    const float* __restrict__ lb,       // (1024,)
    const float* __restrict__ ws,       // xT / h0T / c0T
    float* __restrict__ out)            // h_new | c_new | next_section
{
    const int j   = blockIdx.x;         // column pair index, 0..127
    const int tid = threadIdx.x;

    __shared__ float s_x[256][64];
    __shared__ float s_h[256][64];
    __shared__ float s_z[8][65];

    // stage xT and h0T (64 KB each), coalesced float4 copy
    {
        const float4* srcx = (const float4*)(ws + WS_XT);
        const float4* srch = (const float4*)(ws + WS_H0T);
        float4* dstx = (float4*)&s_x[0][0];
        float4* dsth = (float4*)&s_h[0][0];
        #pragma unroll
        for (int idx = tid; idx < 4096; idx += 512) {
            dstx[idx] = srcx[idx];
            dsth[idx] = srch[idx];
        }
    }
    __syncthreads();

    // b = lane-over-batch, zc in [0,8): gate g = zc>>1, col pair cl = zc&1
    {
        const int b  = tid & 63;
        const int zc = tid >> 6;
        const int g  = zc >> 1;
        const int cl = zc & 1;
        const int col  = j * 2 + cl;          // 0..255
        const int zcol = g * 256 + col;       // 0..1023
        const float* lkp = lk  + zcol;
        const float* lrp = lrk + zcol;
        float acc = lb[zcol];
        #pragma unroll 8
        for (int k = 0; k < 256; ++k)
            acc += s_x[k][b] * lkp[k * 1024] + s_h[k][b] * lrp[k * 1024];
        s_z[zc][b] = acc;
    }
    __syncthreads();

    // cell update: 128 outputs (64 b x 2 cols)
    if (tid < 128) {
        const int b  = tid >> 1;
        const int cl = tid & 1;
        const int col = j * 2 + cl;
        const float zi = s_z[0 + cl][b];
        const float zf = s_z[2 + cl][b];
        const float zg = s_z[4 + cl][b];
        const float zo = s_z[6 + cl][b];
        const float cprev = ws[WS_C0T + col * 64 + b];
        const float cn = sigmoidf_(zf) * cprev + sigmoidf_(zi) * tanhf_(zg);
        const float hn = sigmoidf_(zo) * tanhf_(cn);
        out[b * UNITS + col] = hn;                      // h_new
        out[BATCH * UNITS + b * UNITS + col] = cn;      // c_new
    }
}

// ---------------------------------------------------------------------------
// K3: nsc head. 64 blocks (one per batch), reads h_new back from `out`.
// ---------------------------------------------------------------------------
__global__ __launch_bounds__(1024) void nsc_kernel(
    const float* __restrict__ w1,       // (256,256)
    const float* __restrict__ nb1,      // (256,)
    const float* __restrict__ w2,       // (256,3)
    const float* __restrict__ nb2,      // (3,)
    float* __restrict__ out)
{
    const int b   = blockIdx.x;
    const int tid = threadIdx.x;

    __shared__ float s_hn[256];
    __shared__ float s_nsc[256];
    __shared__ float s_part[4][256];

    if (tid < 256) s_hn[tid] = out[b * UNITS + tid];
    __syncthreads();

    // nsc layer 1: 256 -> 256 + relu, 4-way K split
    {
        const int g = tid >> 8, col = tid & 255;
        const float* wp = w1 + (g * 64) * 256 + col;
        const float* hp = s_hn + g * 64;
        float acc = 0.0f;
        #pragma unroll 8
        for (int k = 0; k < 64; ++k)
            acc += hp[k] * wp[k * 256];
        s_part[g][col] = acc;
    }
    __syncthreads();
    if (tid < 256)
        s_nsc[tid] = fmaxf(s_part[0][tid] + s_part[1][tid] + s_part[2][tid] +
                           s_part[3][tid] + nb1[tid], 0.0f);
    __syncthreads();

    // nsc layer 2: 256 -> 3, sigmoid. One wave per output column.
    if (tid < 192) {
        const int j = tid >> 6;
        const int l = tid & 63;
        float p = 0.0f;
        #pragma unroll
        for (int k = l; k < 256; k += 64)
            p += s_nsc[k] * w2[k * 3 + j];
        #pragma unroll
        for (int off = 32; off > 0; off >>= 1)
            p += __shfl_down(p, off);
        if (l == 0)
            out[2 * BATCH * UNITS + b * 3 + j] = sigmoidf_(p + nb2[j]);
    }
}

extern "C" void kernel_launch(void* const* d_in, const int* in_sizes, int n_in,
                              void* d_out, int out_size, void* d_ws, size_t ws_size,
                              hipStream_t stream) {
    const float* image   = (const float*)d_in[0];
    const float* section = (const float*)d_in[1];
    const float* h0      = (const float*)d_in[2];
    const float* c0      = (const float*)d_in[3];
    const float* k1      = (const float*)d_in[4];
    const float* b1      = (const float*)d_in[5];
    const float* k2      = (const float*)d_in[6];
    const float* b2      = (const float*)d_in[7];
    const float* dw      = (const float*)d_in[8];
    const float* db      = (const float*)d_in[9];
    const float* lk      = (const float*)d_in[10];
    const float* lrk     = (const float*)d_in[11];
    const float* lb      = (const float*)d_in[12];
    const float* w1      = (const float*)d_in[13];
    const float* nb1     = (const float*)d_in[14];
    const float* w2      = (const float*)d_in[15];
    const float* nb2     = (const float*)d_in[16];
    float* out = (float*)d_out;
    float* ws  = (float*)d_ws;

    prep_kernel<<<256, 256, 0, stream>>>(
        image, section, h0, c0, k1, b1, k2, b2, dw, db, ws);
    lstm_kernel<<<128, 512, 0, stream>>>(lk, lrk, lb, ws, out);
    nsc_kernel<<<64, 1024, 0, stream>>>(w1, nb1, w2, nb2, out);
}